// Round 9
// baseline (51.975 us; speedup 1.0000x reference)
//
#include <hip/hip_runtime.h>
#include <hip/hip_bf16.h>
#include <math.h>

#define CIN 256
#define COUT 768   // 3 * OUTC
#define OUTC 256
#define HH 64
#define WW 64
#define HW 4096

typedef unsigned int uint32;
typedef unsigned short ushort16;

using short8 = __attribute__((ext_vector_type(8))) short;
using f32x4  = __attribute__((ext_vector_type(4))) float;

__device__ inline uint32 pkbf2(float a, float b) {
    __hip_bfloat162 h = __float22bfloat162_rn(make_float2(a, b));
    union { __hip_bfloat162 h2; uint32 u; } cv; cv.h2 = h;
    return cv.u;
}
__device__ inline uint32 pkhf2(float a, float b) {
    union { _Float16 h[2]; uint32 u; } cv;
    cv.h[0] = (_Float16)a; cv.h[1] = (_Float16)b;
    return cv.u;
}
__device__ inline float f16lo(uint32 u) {
    union { uint32 u; _Float16 h[2]; } c; c.u = u; return (float)c.h[0];
}
__device__ inline float f16hi(uint32 u) {
    union { uint32 u; _Float16 h[2]; } c; c.u = u; return (float)c.h[1];
}
__device__ inline float dpp_xor1(float x) {
#if __has_builtin(__builtin_amdgcn_update_dpp)
    int i = __builtin_amdgcn_update_dpp(0, __float_as_int(x),
                                        0xB1, 0xF, 0xF, true);
    return __int_as_float(i);
#else
    return __shfl_xor(x, 1, 64);
#endif
}

// ---------------------------------------------------------------------------
// Kernel 1 (v4): QKV projection, bf16 MFMA, 128x128 tile, BK=128 per round.
// Two staging rounds per block; 3 barriers total (vs 16 in R4 / R8's per-kt
// chains -> latency-bound, all pipes <20%). LDS is K-MAJOR [k-unit][row]:
//   cell(u, r) = 16 B = 8 bf16 k's (k = u*8..u*8+7) for row r.
// All LDS reads AND writes are consecutive-cell per lane -> conflict-free,
// no swizzle needed. Staging: A 16xfloat4/thread (coalesced), B 64 scalar
// loads/thread (each instr = 256 B contiguous across lanes).
// Output: qkv_f16[n][slot=d>>5][p][dlow=d&31]  (identical math to R4)
// ---------------------------------------------------------------------------
__global__ __launch_bounds__(256) void qkv_gemm_kernel(
    const float* __restrict__ x, const float* __restrict__ wq,
    const float* __restrict__ bq, ushort16* __restrict__ qkv)
{
    __shared__ uint4 As[2048];   // [16 u][128 d]  32 KB
    __shared__ uint4 Bs[2048];   // [16 u][128 p]  32 KB

    const int n   = blockIdx.z;
    const int d0  = blockIdx.y * 128;
    const int p0  = blockIdx.x * 128;
    const int tid = threadIdx.x;
    const int lane = tid & 63;
    const int wid  = tid >> 6;
    const int wm = wid >> 1, wn = wid & 1;
    const int lrow = lane & 15;
    const int kc   = lane >> 4;        // fragment k-chunk 0..3

    // A staging: thread -> row ar = tid>>1, k-half akh = tid&1 (64 k's)
    const int ar  = tid >> 1;
    const int akh = tid & 1;
    // B staging: thread -> pixel bp = tid&127, c-group bg = tid>>7 (64 c's)
    const int bp = tid & 127;
    const int bg = tid >> 7;

    const float* xb = x + (size_t)n * CIN * HW;

    f32x4 acc[4][4];
    #pragma unroll
    for (int i = 0; i < 4; ++i)
        #pragma unroll
        for (int j = 0; j < 4; ++j) acc[i][j] = (f32x4){0.f, 0.f, 0.f, 0.f};

    #pragma unroll
    for (int kh = 0; kh < 2; ++kh) {
        const int k0 = kh * 128;
        if (kh) __syncthreads();   // previous round's readers done

        // ---- stage A: W[d0+ar][k0 + akh*64 + 0..63] ----
        {
            const float* ap = wq + (size_t)(d0 + ar) * CIN + k0 + akh * 64;
            #pragma unroll
            for (int j = 0; j < 8; ++j) {
                float4 v0 = *(const float4*)(ap + j * 8);
                float4 v1 = *(const float4*)(ap + j * 8 + 4);
                As[(akh * 8 + j) * 128 + ar] =
                    make_uint4(pkbf2(v0.x, v0.y), pkbf2(v0.z, v0.w),
                               pkbf2(v1.x, v1.y), pkbf2(v1.z, v1.w));
            }
        }
        // ---- stage B: x[k0 + bg*64 + 0..63][p0 + bp] ----
        {
            const float* bptr = xb + (size_t)(k0 + bg * 64) * HW + p0 + bp;
            #pragma unroll
            for (int j = 0; j < 8; ++j) {
                float c0 = bptr[(size_t)(j * 8 + 0) * HW];
                float c1 = bptr[(size_t)(j * 8 + 1) * HW];
                float c2 = bptr[(size_t)(j * 8 + 2) * HW];
                float c3 = bptr[(size_t)(j * 8 + 3) * HW];
                float c4 = bptr[(size_t)(j * 8 + 4) * HW];
                float c5 = bptr[(size_t)(j * 8 + 5) * HW];
                float c6 = bptr[(size_t)(j * 8 + 6) * HW];
                float c7 = bptr[(size_t)(j * 8 + 7) * HW];
                Bs[(bg * 8 + j) * 128 + bp] =
                    make_uint4(pkbf2(c0, c1), pkbf2(c2, c3),
                               pkbf2(c4, c5), pkbf2(c6, c7));
            }
        }

        __syncthreads();   // tile ready

        // ---- compute: 4 kt, no barriers, no global deps ----
        #pragma unroll
        for (int kt = 0; kt < 4; ++kt) {
            short8 af[4], bf[4];
            #pragma unroll
            for (int fm = 0; fm < 4; ++fm)
                af[fm] = *(const short8*)&As[(kt * 4 + kc) * 128 + wm * 64 + fm * 16 + lrow];
            #pragma unroll
            for (int fn = 0; fn < 4; ++fn)
                bf[fn] = *(const short8*)&Bs[(kt * 4 + kc) * 128 + wn * 64 + fn * 16 + lrow];
            #pragma unroll
            for (int fm = 0; fm < 4; ++fm)
                #pragma unroll
                for (int fn = 0; fn < 4; ++fn)
                    acc[fm][fn] = __builtin_amdgcn_mfma_f32_16x16x32_bf16(
                        af[fm], bf[fn], acc[fm][fn], 0, 0, 0);
        }
    }

    // ---- epilogue: bias + cvt fp16 + store packed [n][slot][p][dlow] ----
    const int hi4 = lane >> 4;
    ushort16* qn = qkv + (size_t)n * COUT * HW;
    #pragma unroll
    for (int fm = 0; fm < 4; ++fm) {
        const int D = d0 + wm * 64 + fm * 16 + hi4 * 4;
        const float4 bias = *(const float4*)(&bq[D]);
        const int slot = D >> 5, dlow = D & 31;
        ushort16* qs = qn + (size_t)slot * (HW * 32) + dlow;
        #pragma unroll
        for (int fn = 0; fn < 4; ++fn) {
            const int p = p0 + wn * 64 + fn * 16 + lrow;
            f32x4 v = acc[fm][fn];
            uint32 u0 = pkhf2(v[0] + bias.x, v[1] + bias.y);
            uint32 u1 = pkhf2(v[2] + bias.z, v[3] + bias.w);
            *(uint2*)(qs + (size_t)p * 32) = make_uint2(u0, u1);
        }
    }
}

// ---------------------------------------------------------------------------
// Kernel 2: 5x5 neighborhood attention (EXACT R4 body, measured 23.5 us).
// ---------------------------------------------------------------------------
#define TR 4
#define TC 32
#define HR 8
#define HC 36
#define NPIX (HR*HC)  // 288

__global__ __launch_bounds__(256) void attn_kernel(
    const ushort16* __restrict__ qkv, float* __restrict__ out)
{
    __shared__ uint4 Ks[NPIX * 4];   // 18 KB
    __shared__ uint4 Vs[NPIX * 4];   // 18 KB

    const int n    = blockIdx.z;
    const int head = blockIdx.y;
    const int ht = blockIdx.x >> 1;
    const int wt = blockIdx.x & 1;
    const int h0 = ht * TR;
    const int w0 = wt * TC;

    const int tid  = threadIdx.x;
    const int half = tid & 1;
    const int wc   = (tid >> 1) & 31;
    const int tr   = tid >> 6;

    const int h = h0 + tr, w = w0 + wc;
    const int p = h * WW + w;

    const uint4* Kb = (const uint4*)(qkv + ((size_t)(n * 24 + 8 + head)) * HW * 32);
    const uint4* Vb = (const uint4*)(qkv + ((size_t)(n * 24 + 16 + head)) * HW * 32);

    for (int c = tid; c < 2 * NPIX * 4; c += 256) {
        const int b  = (c >= NPIX * 4);
        const int cc = c - b * NPIX * 4;
        const int pix = cc >> 2, i = cc & 3;
        const int hr = pix / HC, cw = pix - hr * HC;
        const int hh = h0 + hr - 2, ww = w0 + cw - 2;
        if (hh >= 0 && hh < HH && ww >= 0 && ww < WW) {
            const int pp = hh * WW + ww;
            const uint4 v = (b ? Vb : Kb)[(size_t)pp * 4 + i];
            const int unit = (pix * 4 + i) ^ (pix & 7);
            (b ? Vs : Ks)[unit] = v;
        }
    }

    float qf[16];
    {
        const uint4* Qp = (const uint4*)(qkv + (((size_t)(n * 24 + head)) * HW + p) * 32);
        #pragma unroll
        for (int i = 0; i < 2; ++i) {
            uint4 u = Qp[half * 2 + i];
            qf[8*i+0] = f16lo(u.x); qf[8*i+1] = f16hi(u.x);
            qf[8*i+2] = f16lo(u.y); qf[8*i+3] = f16hi(u.y);
            qf[8*i+4] = f16lo(u.z); qf[8*i+5] = f16hi(u.z);
            qf[8*i+6] = f16lo(u.w); qf[8*i+7] = f16hi(u.w);
        }
    }

    __syncthreads();

    float sc[25];
    #pragma unroll
    for (int ky = 0; ky < 5; ++ky) {
        const int hh = h + ky - 2;
        const int hr = tr + ky;
        #pragma unroll
        for (int kx = 0; kx < 5; ++kx) {
            const int ww = w + kx - 2;
            float s;
            if (hh >= 0 && hh < HH && ww >= 0 && ww < WW) {
                const int pix = hr * HC + (wc + kx);
                const int u0 = (pix * 4 + half * 2)     ^ (pix & 7);
                const int u1 = (pix * 4 + half * 2 + 1) ^ (pix & 7);
                uint4 a = Ks[u0], b = Ks[u1];
                float t = 0.f;
                t = fmaf(qf[0],  f16lo(a.x), t); t = fmaf(qf[1],  f16hi(a.x), t);
                t = fmaf(qf[2],  f16lo(a.y), t); t = fmaf(qf[3],  f16hi(a.y), t);
                t = fmaf(qf[4],  f16lo(a.z), t); t = fmaf(qf[5],  f16hi(a.z), t);
                t = fmaf(qf[6],  f16lo(a.w), t); t = fmaf(qf[7],  f16hi(a.w), t);
                t = fmaf(qf[8],  f16lo(b.x), t); t = fmaf(qf[9],  f16hi(b.x), t);
                t = fmaf(qf[10], f16lo(b.y), t); t = fmaf(qf[11], f16hi(b.y), t);
                t = fmaf(qf[12], f16lo(b.z), t); t = fmaf(qf[13], f16hi(b.z), t);
                t = fmaf(qf[14], f16lo(b.w), t); t = fmaf(qf[15], f16hi(b.w), t);
                s = t;
            } else {
                s = -1e30f;
            }
            sc[ky * 5 + kx] = s;
        }
    }
    #pragma unroll
    for (int k = 0; k < 25; ++k) {
        float o = dpp_xor1(sc[k]);
        sc[k] = (sc[k] <= -1e29f) ? sc[k] : sc[k] + o;
    }

    float m = sc[0];
    #pragma unroll
    for (int k = 1; k < 25; ++k) m = fmaxf(m, sc[k]);
    float sum = 0.f;
    #pragma unroll
    for (int k = 0; k < 25; ++k) {
        float e = __expf(sc[k] - m);
        sc[k] = e;
        sum += e;
    }
    const float inv = 1.f / sum;

    float al[8], ah[8];
    #pragma unroll
    for (int i = 0; i < 8; ++i) { al[i] = 0.f; ah[i] = 0.f; }
    #pragma unroll
    for (int ky = 0; ky < 5; ++ky) {
        const int hh = h + ky - 2;
        if (hh < 0 || hh >= HH) continue;
        const int hr = tr + ky;
        #pragma unroll
        for (int kx = 0; kx < 5; ++kx) {
            const int ww = w + kx - 2;
            if (ww < 0 || ww >= WW) continue;
            const float a = sc[ky * 5 + kx];
            const int pix = hr * HC + (wc + kx);
            const int u0 = (pix * 4 + half * 2)     ^ (pix & 7);
            const int u1 = (pix * 4 + half * 2 + 1) ^ (pix & 7);
            uint4 xv = Vs[u0], yv = Vs[u1];
            al[0] = fmaf(a, f16lo(xv.x), al[0]); ah[0] = fmaf(a, f16hi(xv.x), ah[0]);
            al[1] = fmaf(a, f16lo(xv.y), al[1]); ah[1] = fmaf(a, f16hi(xv.y), ah[1]);
            al[2] = fmaf(a, f16lo(xv.z), al[2]); ah[2] = fmaf(a, f16hi(xv.z), ah[2]);
            al[3] = fmaf(a, f16lo(xv.w), al[3]); ah[3] = fmaf(a, f16hi(xv.w), ah[3]);
            al[4] = fmaf(a, f16lo(yv.x), al[4]); ah[4] = fmaf(a, f16hi(yv.x), ah[4]);
            al[5] = fmaf(a, f16lo(yv.y), al[5]); ah[5] = fmaf(a, f16hi(yv.y), ah[5]);
            al[6] = fmaf(a, f16lo(yv.z), al[6]); ah[6] = fmaf(a, f16hi(yv.z), ah[6]);
            al[7] = fmaf(a, f16lo(yv.w), al[7]); ah[7] = fmaf(a, f16hi(yv.w), ah[7]);
        }
    }

    float* Ob = out + ((size_t)(n * 8 + head) * 32 + half * 16) * HW + p;
    #pragma unroll
    for (int i = 0; i < 8; ++i) {
        Ob[(size_t)(2*i)   * HW] = al[i] * inv;
        Ob[(size_t)(2*i+1) * HW] = ah[i] * inv;
    }
}

// ---------------------------------------------------------------------------
extern "C" void kernel_launch(void* const* d_in, const int* in_sizes, int n_in,
                              void* d_out, int out_size, void* d_ws, size_t ws_size,
                              hipStream_t stream) {
    const float* x  = (const float*)d_in[0];   // (4, 256, 64, 64)
    const float* wq = (const float*)d_in[1];   // (768, 256)
    const float* bq = (const float*)d_in[2];   // (768,)
    float* out = (float*)d_out;                // (4, 256, 64, 64) fp32
    ushort16* qkv = (ushort16*)d_ws;           // fp16 [4][24][4096][32] = 25 MB

    dim3 g1(HW / 128, COUT / 128, 4);          // (32, 6, 4) = 768 blocks
    qkv_gemm_kernel<<<g1, 256, 0, stream>>>(x, wq, bq, qkv);

    dim3 g2(32, 8, 4);
    attn_kernel<<<g2, 256, 0, stream>>>(qkv, out);
}

// Round 10
// 45.534 us; speedup vs baseline: 1.1415x; 1.1415x over previous
//
#include <hip/hip_runtime.h>
#include <hip/hip_bf16.h>
#include <math.h>

#define CIN 256
#define COUT 768   // 3 * OUTC
#define OUTC 256
#define HH 64
#define WW 64
#define HW 4096

typedef unsigned int uint32;
typedef unsigned short ushort16;
typedef unsigned long long u64;

using short8 = __attribute__((ext_vector_type(8))) short;
using f32x4  = __attribute__((ext_vector_type(4))) float;

__device__ inline uint32 pkbf2(float a, float b) {
    __hip_bfloat162 h = __float22bfloat162_rn(make_float2(a, b));
    union { __hip_bfloat162 h2; uint32 u; } cv; cv.h2 = h;
    return cv.u;
}
__device__ inline uint32 pkhf2(float a, float b) {
    union { _Float16 h[2]; uint32 u; } cv;
    cv.h[0] = (_Float16)a; cv.h[1] = (_Float16)b;
    return cv.u;
}
__device__ inline float f16lo(uint32 u) {
    union { uint32 u; _Float16 h[2]; } c; c.u = u; return (float)c.h[0];
}
__device__ inline float f16hi(uint32 u) {
    union { uint32 u; _Float16 h[2]; } c; c.u = u; return (float)c.h[1];
}
__device__ inline float dpp_xor1(float x) {
#if __has_builtin(__builtin_amdgcn_update_dpp)
    int i = __builtin_amdgcn_update_dpp(0, __float_as_int(x),
                                        0xB1, 0xF, 0xF, true);
    return __int_as_float(i);
#else
    return __shfl_xor(x, 1, 64);
#endif
}

// ---------------------------------------------------------------------------
// Kernel 1 (v5): R4's reg-staged MFMA loop (best measured: 23.6us) with a
// NEW LDS-transposed epilogue. Old epilogue: 32 scattered 8-B stores/thread
// (each wave-store touches 64 L2 lines -> ~10us, constant across R4/R5/R8/R9
// structures). New: pack fp16 to per-wave 8-KB LDS region (XOR-swizzled),
// read back d-major, 8 coalesced 1-KB wave-stores.
// Output layout unchanged: qkv_f16[n][slot=d>>5][p][dlow=d&31]
// ---------------------------------------------------------------------------
#define LDSTR 40   // shorts per LDS row (32 + 8 pad)

__global__ __launch_bounds__(256) void qkv_gemm_kernel(
    const float* __restrict__ x, const float* __restrict__ wq,
    const float* __restrict__ bq, ushort16* __restrict__ qkv)
{
    // union: staging (As 10240 B + Bs 10240 B) | epilogue buffer (32 KB)
    __shared__ __align__(16) char smem[32768];
    ushort16* As = (ushort16*)smem;            // [128][LDSTR]
    ushort16* Bs = (ushort16*)smem + 128 * LDSTR;

    const int n   = blockIdx.z;
    const int d0  = blockIdx.y * 128;
    const int p0  = blockIdx.x * 128;
    const int tid = threadIdx.x;
    const int lane = tid & 63;
    const int wid  = tid >> 6;
    const int wm = wid >> 1;
    const int wn = wid & 1;

    const float* xb = x + (size_t)n * CIN * HW;

    const int arow = tid >> 2;
    const int akk  = (tid & 3) * 8;
    const float* aptr = wq + (size_t)(d0 + arow) * CIN + akk;
    const int bkg = (tid >> 6) * 8;
    const int bpg = (tid & 63) * 2;
    const float* bptr = xb + (size_t)bkg * HW + p0 + bpg;

    ushort16* awr0 = &As[arow * LDSTR + akk];
    ushort16* awr1 = &As[(arow + 64) * LDSTR + akk];
    ushort16* bwr0 = &Bs[bpg * LDSTR + bkg];
    ushort16* bwr1 = &Bs[(bpg + 1) * LDSTR + bkg];

    f32x4 acc[4][4];
    #pragma unroll
    for (int i = 0; i < 4; ++i)
        #pragma unroll
        for (int j = 0; j < 4; ++j) acc[i][j] = (f32x4){0.f, 0.f, 0.f, 0.f};

    float4 a_st[4];
    float2 b_st[8];

    {
        a_st[0] = *(const float4*)(aptr);
        a_st[1] = *(const float4*)(aptr + 4);
        a_st[2] = *(const float4*)(aptr + (size_t)64 * CIN);
        a_st[3] = *(const float4*)(aptr + (size_t)64 * CIN + 4);
        #pragma unroll
        for (int j = 0; j < 8; ++j)
            b_st[j] = *(const float2*)(bptr + (size_t)j * HW);
    }

    const int lrow = lane & 15;
    const int lk   = (lane >> 4) * 8;

    #pragma unroll 1
    for (int kt = 0; kt < 8; ++kt) {
        __syncthreads();

        {
            uint32 w0 = pkbf2(a_st[0].x, a_st[0].y), w1 = pkbf2(a_st[0].z, a_st[0].w);
            uint32 w2 = pkbf2(a_st[1].x, a_st[1].y), w3 = pkbf2(a_st[1].z, a_st[1].w);
            *(uint4*)awr0 = make_uint4(w0, w1, w2, w3);
            w0 = pkbf2(a_st[2].x, a_st[2].y); w1 = pkbf2(a_st[2].z, a_st[2].w);
            w2 = pkbf2(a_st[3].x, a_st[3].y); w3 = pkbf2(a_st[3].z, a_st[3].w);
            *(uint4*)awr1 = make_uint4(w0, w1, w2, w3);
            uint4 c0, c1;
            c0.x = pkbf2(b_st[0].x, b_st[1].x); c0.y = pkbf2(b_st[2].x, b_st[3].x);
            c0.z = pkbf2(b_st[4].x, b_st[5].x); c0.w = pkbf2(b_st[6].x, b_st[7].x);
            c1.x = pkbf2(b_st[0].y, b_st[1].y); c1.y = pkbf2(b_st[2].y, b_st[3].y);
            c1.z = pkbf2(b_st[4].y, b_st[5].y); c1.w = pkbf2(b_st[6].y, b_st[7].y);
            *(uint4*)bwr0 = c0;
            *(uint4*)bwr1 = c1;
        }

        if (kt < 7) {
            const int ko = (kt + 1) * 32;
            a_st[0] = *(const float4*)(aptr + ko);
            a_st[1] = *(const float4*)(aptr + ko + 4);
            a_st[2] = *(const float4*)(aptr + (size_t)64 * CIN + ko);
            a_st[3] = *(const float4*)(aptr + (size_t)64 * CIN + ko + 4);
            #pragma unroll
            for (int j = 0; j < 8; ++j)
                b_st[j] = *(const float2*)(bptr + (size_t)(ko + j) * HW);
        }

        __syncthreads();

        short8 af[4], bf[4];
        #pragma unroll
        for (int fm = 0; fm < 4; ++fm)
            af[fm] = *(const short8*)&As[(wm * 64 + fm * 16 + lrow) * LDSTR + lk];
        #pragma unroll
        for (int fn = 0; fn < 4; ++fn)
            bf[fn] = *(const short8*)&Bs[(wn * 64 + fn * 16 + lrow) * LDSTR + lk];
        #pragma unroll
        for (int fm = 0; fm < 4; ++fm)
            #pragma unroll
            for (int fn = 0; fn < 4; ++fn)
                acc[fm][fn] = __builtin_amdgcn_mfma_f32_16x16x32_bf16(
                    af[fm], bf[fn], acc[fm][fn], 0, 0, 0);
    }

    // ---- epilogue v2: LDS transpose -> coalesced stores ----
    __syncthreads();   // all waves done reading As/Bs (E aliases them)

    // E: per-wave 8-KB region = [64 p][8 cells x 16 B], cell swizzle ^(p&7)
    u64* E = (u64*)smem + (size_t)wid * 1024;   // 1024 x 8 B

    const int hi4 = lane >> 4;
    #pragma unroll
    for (int fm = 0; fm < 4; ++fm) {
        const int D = d0 + wm * 64 + fm * 16 + hi4 * 4;   // d of v[0..3]
        const float4 bias = *(const float4*)(&bq[D]);
        const int cell = fm * 2 + (hi4 >> 1);             // 16-B cell 0..7
        const int half = hi4 & 1;                         // 8-B half
        #pragma unroll
        for (int fn = 0; fn < 4; ++fn) {
            const int pl = fn * 16 + lrow;                // p-local 0..63
            f32x4 v = acc[fm][fn];
            u64 pk = (u64)pkhf2(v[0] + bias.x, v[1] + bias.y)
                   | ((u64)pkhf2(v[2] + bias.z, v[3] + bias.w) << 32);
            E[pl * 16 + (cell ^ (pl & 7)) * 2 + half] = pk;
        }
    }
    // read back d-major, store 1-KB contiguous runs
    const int pl4 = lane >> 2;     // p within 16-group
    const int dq  = lane & 3;      // 16-B quarter within a slot's 64-B row
    ushort16* qn = qkv + (size_t)n * COUT * HW;
    #pragma unroll
    for (int s = 0; s < 2; ++s) {                 // slot half (32 d each)
        const int D = d0 + wm * 64 + s * 32;
        const int slot = D >> 5;
        ushort16* sb = qn + (size_t)slot * (HW * 32);
        #pragma unroll
        for (int g = 0; g < 4; ++g) {             // p-group of 16
            const int prow = g * 16 + pl4;
            const int c = s * 4 + dq;
            const uint4 val = *(const uint4*)&E[prow * 16 + ((c ^ (prow & 7)) * 2)];
            *(uint4*)(sb + (size_t)(p0 + wn * 64 + prow) * 32 + dq * 8) = val;
        }
    }
}

// ---------------------------------------------------------------------------
// Kernel 2: 5x5 neighborhood attention (EXACT R4 body, measured 23.5 us).
// ---------------------------------------------------------------------------
#define TR 4
#define TC 32
#define HR 8
#define HC 36
#define NPIX (HR*HC)  // 288

__global__ __launch_bounds__(256) void attn_kernel(
    const ushort16* __restrict__ qkv, float* __restrict__ out)
{
    __shared__ uint4 Ks[NPIX * 4];   // 18 KB
    __shared__ uint4 Vs[NPIX * 4];   // 18 KB

    const int n    = blockIdx.z;
    const int head = blockIdx.y;
    const int ht = blockIdx.x >> 1;
    const int wt = blockIdx.x & 1;
    const int h0 = ht * TR;
    const int w0 = wt * TC;

    const int tid  = threadIdx.x;
    const int half = tid & 1;
    const int wc   = (tid >> 1) & 31;
    const int tr   = tid >> 6;

    const int h = h0 + tr, w = w0 + wc;
    const int p = h * WW + w;

    const uint4* Kb = (const uint4*)(qkv + ((size_t)(n * 24 + 8 + head)) * HW * 32);
    const uint4* Vb = (const uint4*)(qkv + ((size_t)(n * 24 + 16 + head)) * HW * 32);

    for (int c = tid; c < 2 * NPIX * 4; c += 256) {
        const int b  = (c >= NPIX * 4);
        const int cc = c - b * NPIX * 4;
        const int pix = cc >> 2, i = cc & 3;
        const int hr = pix / HC, cw = pix - hr * HC;
        const int hh = h0 + hr - 2, ww = w0 + cw - 2;
        if (hh >= 0 && hh < HH && ww >= 0 && ww < WW) {
            const int pp = hh * WW + ww;
            const uint4 v = (b ? Vb : Kb)[(size_t)pp * 4 + i];
            const int unit = (pix * 4 + i) ^ (pix & 7);
            (b ? Vs : Ks)[unit] = v;
        }
    }

    float qf[16];
    {
        const uint4* Qp = (const uint4*)(qkv + (((size_t)(n * 24 + head)) * HW + p) * 32);
        #pragma unroll
        for (int i = 0; i < 2; ++i) {
            uint4 u = Qp[half * 2 + i];
            qf[8*i+0] = f16lo(u.x); qf[8*i+1] = f16hi(u.x);
            qf[8*i+2] = f16lo(u.y); qf[8*i+3] = f16hi(u.y);
            qf[8*i+4] = f16lo(u.z); qf[8*i+5] = f16hi(u.z);
            qf[8*i+6] = f16lo(u.w); qf[8*i+7] = f16hi(u.w);
        }
    }

    __syncthreads();

    float sc[25];
    #pragma unroll
    for (int ky = 0; ky < 5; ++ky) {
        const int hh = h + ky - 2;
        const int hr = tr + ky;
        #pragma unroll
        for (int kx = 0; kx < 5; ++kx) {
            const int ww = w + kx - 2;
            float s;
            if (hh >= 0 && hh < HH && ww >= 0 && ww < WW) {
                const int pix = hr * HC + (wc + kx);
                const int u0 = (pix * 4 + half * 2)     ^ (pix & 7);
                const int u1 = (pix * 4 + half * 2 + 1) ^ (pix & 7);
                uint4 a = Ks[u0], b = Ks[u1];
                float t = 0.f;
                t = fmaf(qf[0],  f16lo(a.x), t); t = fmaf(qf[1],  f16hi(a.x), t);
                t = fmaf(qf[2],  f16lo(a.y), t); t = fmaf(qf[3],  f16hi(a.y), t);
                t = fmaf(qf[4],  f16lo(a.z), t); t = fmaf(qf[5],  f16hi(a.z), t);
                t = fmaf(qf[6],  f16lo(a.w), t); t = fmaf(qf[7],  f16hi(a.w), t);
                t = fmaf(qf[8],  f16lo(b.x), t); t = fmaf(qf[9],  f16hi(b.x), t);
                t = fmaf(qf[10], f16lo(b.y), t); t = fmaf(qf[11], f16hi(b.y), t);
                t = fmaf(qf[12], f16lo(b.z), t); t = fmaf(qf[13], f16hi(b.z), t);
                t = fmaf(qf[14], f16lo(b.w), t); t = fmaf(qf[15], f16hi(b.w), t);
                s = t;
            } else {
                s = -1e30f;
            }
            sc[ky * 5 + kx] = s;
        }
    }
    #pragma unroll
    for (int k = 0; k < 25; ++k) {
        float o = dpp_xor1(sc[k]);
        sc[k] = (sc[k] <= -1e29f) ? sc[k] : sc[k] + o;
    }

    float m = sc[0];
    #pragma unroll
    for (int k = 1; k < 25; ++k) m = fmaxf(m, sc[k]);
    float sum = 0.f;
    #pragma unroll
    for (int k = 0; k < 25; ++k) {
        float e = __expf(sc[k] - m);
        sc[k] = e;
        sum += e;
    }
    const float inv = 1.f / sum;

    float al[8], ah[8];
    #pragma unroll
    for (int i = 0; i < 8; ++i) { al[i] = 0.f; ah[i] = 0.f; }
    #pragma unroll
    for (int ky = 0; ky < 5; ++ky) {
        const int hh = h + ky - 2;
        if (hh < 0 || hh >= HH) continue;
        const int hr = tr + ky;
        #pragma unroll
        for (int kx = 0; kx < 5; ++kx) {
            const int ww = w + kx - 2;
            if (ww < 0 || ww >= WW) continue;
            const float a = sc[ky * 5 + kx];
            const int pix = hr * HC + (wc + kx);
            const int u0 = (pix * 4 + half * 2)     ^ (pix & 7);
            const int u1 = (pix * 4 + half * 2 + 1) ^ (pix & 7);
            uint4 xv = Vs[u0], yv = Vs[u1];
            al[0] = fmaf(a, f16lo(xv.x), al[0]); ah[0] = fmaf(a, f16hi(xv.x), ah[0]);
            al[1] = fmaf(a, f16lo(xv.y), al[1]); ah[1] = fmaf(a, f16hi(xv.y), ah[1]);
            al[2] = fmaf(a, f16lo(xv.z), al[2]); ah[2] = fmaf(a, f16hi(xv.z), ah[2]);
            al[3] = fmaf(a, f16lo(xv.w), al[3]); ah[3] = fmaf(a, f16hi(xv.w), ah[3]);
            al[4] = fmaf(a, f16lo(yv.x), al[4]); ah[4] = fmaf(a, f16hi(yv.x), ah[4]);
            al[5] = fmaf(a, f16lo(yv.y), al[5]); ah[5] = fmaf(a, f16hi(yv.y), ah[5]);
            al[6] = fmaf(a, f16lo(yv.z), al[6]); ah[6] = fmaf(a, f16hi(yv.z), ah[6]);
            al[7] = fmaf(a, f16lo(yv.w), al[7]); ah[7] = fmaf(a, f16hi(yv.w), ah[7]);
        }
    }

    float* Ob = out + ((size_t)(n * 8 + head) * 32 + half * 16) * HW + p;
    #pragma unroll
    for (int i = 0; i < 8; ++i) {
        Ob[(size_t)(2*i)   * HW] = al[i] * inv;
        Ob[(size_t)(2*i+1) * HW] = ah[i] * inv;
    }
}

// ---------------------------------------------------------------------------
extern "C" void kernel_launch(void* const* d_in, const int* in_sizes, int n_in,
                              void* d_out, int out_size, void* d_ws, size_t ws_size,
                              hipStream_t stream) {
    const float* x  = (const float*)d_in[0];   // (4, 256, 64, 64)
    const float* wq = (const float*)d_in[1];   // (768, 256)
    const float* bq = (const float*)d_in[2];   // (768,)
    float* out = (float*)d_out;                // (4, 256, 64, 64) fp32
    ushort16* qkv = (ushort16*)d_ws;           // fp16 [4][24][4096][32] = 25 MB

    dim3 g1(HW / 128, COUT / 128, 4);          // (32, 6, 4) = 768 blocks
    qkv_gemm_kernel<<<g1, 256, 0, stream>>>(x, wq, bq, qkv);

    dim3 g2(32, 8, 4);
    attn_kernel<<<g2, 256, 0, stream>>>(qkv, out);
}

// Round 11
// 41.775 us; speedup vs baseline: 1.2442x; 1.0900x over previous
//
#include <hip/hip_runtime.h>
#include <hip/hip_bf16.h>
#include <math.h>

#define CIN 256
#define COUT 768   // 3 * OUTC
#define OUTC 256
#define HH 64
#define WW 64
#define HW 4096

typedef unsigned int uint32;
typedef unsigned short ushort16;
typedef unsigned long long u64;

using short8 = __attribute__((ext_vector_type(8))) short;
using f32x4  = __attribute__((ext_vector_type(4))) float;
using hf2    = __attribute__((ext_vector_type(2))) _Float16;

__device__ inline uint32 pkbf2(float a, float b) {
    __hip_bfloat162 h = __float22bfloat162_rn(make_float2(a, b));
    union { __hip_bfloat162 h2; uint32 u; } cv; cv.h2 = h;
    return cv.u;
}
__device__ inline uint32 pkhf2(float a, float b) {
    union { _Float16 h[2]; uint32 u; } cv;
    cv.h[0] = (_Float16)a; cv.h[1] = (_Float16)b;
    return cv.u;
}
__device__ inline float f16lo(uint32 u) {
    union { uint32 u; _Float16 h[2]; } c; c.u = u; return (float)c.h[0];
}
__device__ inline float f16hi(uint32 u) {
    union { uint32 u; _Float16 h[2]; } c; c.u = u; return (float)c.h[1];
}
__device__ inline float dpp_xor1(float x) {
#if __has_builtin(__builtin_amdgcn_update_dpp)
    int i = __builtin_amdgcn_update_dpp(0, __float_as_int(x),
                                        0xB1, 0xF, 0xF, true);
    return __int_as_float(i);
#else
    return __shfl_xor(x, 1, 64);
#endif
}

// f32 += dot(h2, h2) — v_dot2_f32_f16 if available, else unpack-fma
__device__ inline float dot2acc(hf2 a, hf2 b, float c) {
#if __has_builtin(__builtin_amdgcn_fdot2)
    return __builtin_amdgcn_fdot2(a, b, c, false);
#else
    c = fmaf((float)a[0], (float)b[0], c);
    return fmaf((float)a[1], (float)b[1], c);
#endif
}

// ---------------------------------------------------------------------------
// Kernel 1: QKV projection (EXACT R10 body, measured ~22-23 us).
// Output: qkv_f16[n][slot=d>>5][p][dlow=d&31]
// ---------------------------------------------------------------------------
#define LDSTR 40   // shorts per LDS row (32 + 8 pad)

__global__ __launch_bounds__(256) void qkv_gemm_kernel(
    const float* __restrict__ x, const float* __restrict__ wq,
    const float* __restrict__ bq, ushort16* __restrict__ qkv)
{
    __shared__ __align__(16) char smem[32768];
    ushort16* As = (ushort16*)smem;            // [128][LDSTR]
    ushort16* Bs = (ushort16*)smem + 128 * LDSTR;

    const int n   = blockIdx.z;
    const int d0  = blockIdx.y * 128;
    const int p0  = blockIdx.x * 128;
    const int tid = threadIdx.x;
    const int lane = tid & 63;
    const int wid  = tid >> 6;
    const int wm = wid >> 1;
    const int wn = wid & 1;

    const float* xb = x + (size_t)n * CIN * HW;

    const int arow = tid >> 2;
    const int akk  = (tid & 3) * 8;
    const float* aptr = wq + (size_t)(d0 + arow) * CIN + akk;
    const int bkg = (tid >> 6) * 8;
    const int bpg = (tid & 63) * 2;
    const float* bptr = xb + (size_t)bkg * HW + p0 + bpg;

    ushort16* awr0 = &As[arow * LDSTR + akk];
    ushort16* awr1 = &As[(arow + 64) * LDSTR + akk];
    ushort16* bwr0 = &Bs[bpg * LDSTR + bkg];
    ushort16* bwr1 = &Bs[(bpg + 1) * LDSTR + bkg];

    f32x4 acc[4][4];
    #pragma unroll
    for (int i = 0; i < 4; ++i)
        #pragma unroll
        for (int j = 0; j < 4; ++j) acc[i][j] = (f32x4){0.f, 0.f, 0.f, 0.f};

    float4 a_st[4];
    float2 b_st[8];

    {
        a_st[0] = *(const float4*)(aptr);
        a_st[1] = *(const float4*)(aptr + 4);
        a_st[2] = *(const float4*)(aptr + (size_t)64 * CIN);
        a_st[3] = *(const float4*)(aptr + (size_t)64 * CIN + 4);
        #pragma unroll
        for (int j = 0; j < 8; ++j)
            b_st[j] = *(const float2*)(bptr + (size_t)j * HW);
    }

    const int lrow = lane & 15;
    const int lk   = (lane >> 4) * 8;

    #pragma unroll 1
    for (int kt = 0; kt < 8; ++kt) {
        __syncthreads();

        {
            uint32 w0 = pkbf2(a_st[0].x, a_st[0].y), w1 = pkbf2(a_st[0].z, a_st[0].w);
            uint32 w2 = pkbf2(a_st[1].x, a_st[1].y), w3 = pkbf2(a_st[1].z, a_st[1].w);
            *(uint4*)awr0 = make_uint4(w0, w1, w2, w3);
            w0 = pkbf2(a_st[2].x, a_st[2].y); w1 = pkbf2(a_st[2].z, a_st[2].w);
            w2 = pkbf2(a_st[3].x, a_st[3].y); w3 = pkbf2(a_st[3].z, a_st[3].w);
            *(uint4*)awr1 = make_uint4(w0, w1, w2, w3);
            uint4 c0, c1;
            c0.x = pkbf2(b_st[0].x, b_st[1].x); c0.y = pkbf2(b_st[2].x, b_st[3].x);
            c0.z = pkbf2(b_st[4].x, b_st[5].x); c0.w = pkbf2(b_st[6].x, b_st[7].x);
            c1.x = pkbf2(b_st[0].y, b_st[1].y); c1.y = pkbf2(b_st[2].y, b_st[3].y);
            c1.z = pkbf2(b_st[4].y, b_st[5].y); c1.w = pkbf2(b_st[6].y, b_st[7].y);
            *(uint4*)bwr0 = c0;
            *(uint4*)bwr1 = c1;
        }

        if (kt < 7) {
            const int ko = (kt + 1) * 32;
            a_st[0] = *(const float4*)(aptr + ko);
            a_st[1] = *(const float4*)(aptr + ko + 4);
            a_st[2] = *(const float4*)(aptr + (size_t)64 * CIN + ko);
            a_st[3] = *(const float4*)(aptr + (size_t)64 * CIN + ko + 4);
            #pragma unroll
            for (int j = 0; j < 8; ++j)
                b_st[j] = *(const float2*)(bptr + (size_t)(ko + j) * HW);
        }

        __syncthreads();

        short8 af[4], bf[4];
        #pragma unroll
        for (int fm = 0; fm < 4; ++fm)
            af[fm] = *(const short8*)&As[(wm * 64 + fm * 16 + lrow) * LDSTR + lk];
        #pragma unroll
        for (int fn = 0; fn < 4; ++fn)
            bf[fn] = *(const short8*)&Bs[(wn * 64 + fn * 16 + lrow) * LDSTR + lk];
        #pragma unroll
        for (int fm = 0; fm < 4; ++fm)
            #pragma unroll
            for (int fn = 0; fn < 4; ++fn)
                acc[fm][fn] = __builtin_amdgcn_mfma_f32_16x16x32_bf16(
                    af[fm], bf[fn], acc[fm][fn], 0, 0, 0);
    }

    // ---- epilogue: LDS transpose -> coalesced stores (R10) ----
    __syncthreads();

    u64* E = (u64*)smem + (size_t)wid * 1024;

    const int hi4 = lane >> 4;
    #pragma unroll
    for (int fm = 0; fm < 4; ++fm) {
        const int D = d0 + wm * 64 + fm * 16 + hi4 * 4;
        const float4 bias = *(const float4*)(&bq[D]);
        const int cell = fm * 2 + (hi4 >> 1);
        const int half = hi4 & 1;
        #pragma unroll
        for (int fn = 0; fn < 4; ++fn) {
            const int pl = fn * 16 + lrow;
            f32x4 v = acc[fm][fn];
            u64 pk = (u64)pkhf2(v[0] + bias.x, v[1] + bias.y)
                   | ((u64)pkhf2(v[2] + bias.z, v[3] + bias.w) << 32);
            E[pl * 16 + (cell ^ (pl & 7)) * 2 + half] = pk;
        }
    }
    const int pl4 = lane >> 2;
    const int dq  = lane & 3;
    ushort16* qn = qkv + (size_t)n * COUT * HW;
    #pragma unroll
    for (int s = 0; s < 2; ++s) {
        const int D = d0 + wm * 64 + s * 32;
        const int slot = D >> 5;
        ushort16* sb = qn + (size_t)slot * (HW * 32);
        #pragma unroll
        for (int g = 0; g < 4; ++g) {
            const int prow = g * 16 + pl4;
            const int c = s * 4 + dq;
            const uint4 val = *(const uint4*)&E[prow * 16 + ((c ^ (prow & 7)) * 2)];
            *(uint4*)(sb + (size_t)(p0 + wn * 64 + prow) * 32 + dq * 8) = val;
        }
    }
}

// ---------------------------------------------------------------------------
// Kernel 2 (v5): 5x5 neighborhood attention, packed-math.
// QK: Q kept packed half2; 8x v_dot2_f32_f16 per neighbor (chain 16 -> 8).
// PV: half2 accumulators, 8x v_pk_fma_f16 per neighbor (no unpacks).
// Staging / swizzle / DPP combine / softmax identical to R4.
// ---------------------------------------------------------------------------
#define TR 4
#define TC 32
#define HR 8
#define HC 36
#define NPIX (HR*HC)  // 288

__global__ __launch_bounds__(256) void attn_kernel(
    const ushort16* __restrict__ qkv, float* __restrict__ out)
{
    __shared__ uint4 Ks[NPIX * 4];   // 18 KB
    __shared__ uint4 Vs[NPIX * 4];   // 18 KB

    const int n    = blockIdx.z;
    const int head = blockIdx.y;
    const int ht = blockIdx.x >> 1;
    const int wt = blockIdx.x & 1;
    const int h0 = ht * TR;
    const int w0 = wt * TC;

    const int tid  = threadIdx.x;
    const int half = tid & 1;
    const int wc   = (tid >> 1) & 31;
    const int tr   = tid >> 6;

    const int h = h0 + tr, w = w0 + wc;
    const int p = h * WW + w;

    const uint4* Kb = (const uint4*)(qkv + ((size_t)(n * 24 + 8 + head)) * HW * 32);
    const uint4* Vb = (const uint4*)(qkv + ((size_t)(n * 24 + 16 + head)) * HW * 32);

    for (int c = tid; c < 2 * NPIX * 4; c += 256) {
        const int b  = (c >= NPIX * 4);
        const int cc = c - b * NPIX * 4;
        const int pix = cc >> 2, i = cc & 3;
        const int hr = pix / HC, cw = pix - hr * HC;
        const int hh = h0 + hr - 2, ww = w0 + cw - 2;
        if (hh >= 0 && hh < HH && ww >= 0 && ww < WW) {
            const int pp = hh * WW + ww;
            const uint4 v = (b ? Vb : Kb)[(size_t)pp * 4 + i];
            const int unit = (pix * 4 + i) ^ (pix & 7);
            (b ? Vs : Ks)[unit] = v;
        }
    }

    // Q: this thread's 16 dims, KEPT PACKED as 8x half2
    hf2 q[8];
    {
        const uint4* Qp = (const uint4*)(qkv + (((size_t)(n * 24 + head)) * HW + p) * 32);
        union { uint4 u; hf2 h[4]; } c0, c1;
        c0.u = Qp[half * 2];
        c1.u = Qp[half * 2 + 1];
        #pragma unroll
        for (int i = 0; i < 4; ++i) { q[i] = c0.h[i]; q[4 + i] = c1.h[i]; }
    }

    __syncthreads();

    float sc[25];
    #pragma unroll
    for (int ky = 0; ky < 5; ++ky) {
        const int hh = h + ky - 2;
        const int hr = tr + ky;
        #pragma unroll
        for (int kx = 0; kx < 5; ++kx) {
            const int ww = w + kx - 2;
            float s;
            if (hh >= 0 && hh < HH && ww >= 0 && ww < WW) {
                const int pix = hr * HC + (wc + kx);
                const int u0 = (pix * 4 + half * 2)     ^ (pix & 7);
                const int u1 = (pix * 4 + half * 2 + 1) ^ (pix & 7);
                union { uint4 u; hf2 h[4]; } a, b;
                a.u = Ks[u0]; b.u = Ks[u1];
                float t = 0.f;
                t = dot2acc(q[0], a.h[0], t);
                t = dot2acc(q[1], a.h[1], t);
                t = dot2acc(q[2], a.h[2], t);
                t = dot2acc(q[3], a.h[3], t);
                t = dot2acc(q[4], b.h[0], t);
                t = dot2acc(q[5], b.h[1], t);
                t = dot2acc(q[6], b.h[2], t);
                t = dot2acc(q[7], b.h[3], t);
                s = t;
            } else {
                s = -1e30f;
            }
            sc[ky * 5 + kx] = s;
        }
    }
    #pragma unroll
    for (int k = 0; k < 25; ++k) {
        float o = dpp_xor1(sc[k]);
        sc[k] = (sc[k] <= -1e29f) ? sc[k] : sc[k] + o;
    }

    float m = sc[0];
    #pragma unroll
    for (int k = 1; k < 25; ++k) m = fmaxf(m, sc[k]);
    float sum = 0.f;
    #pragma unroll
    for (int k = 0; k < 25; ++k) {
        float e = __expf(sc[k] - m);
        sc[k] = e;
        sum += e;
    }
    const float inv = 1.f / sum;

    // PV: packed half2 accumulate (8 pk_fma per neighbor)
    hf2 acch[8];
    #pragma unroll
    for (int i = 0; i < 8; ++i) acch[i] = (hf2){(_Float16)0.f, (_Float16)0.f};
    #pragma unroll
    for (int ky = 0; ky < 5; ++ky) {
        const int hh = h + ky - 2;
        if (hh < 0 || hh >= HH) continue;
        const int hr = tr + ky;
        #pragma unroll
        for (int kx = 0; kx < 5; ++kx) {
            const int ww = w + kx - 2;
            if (ww < 0 || ww >= WW) continue;
            const _Float16 af = (_Float16)sc[ky * 5 + kx];
            const hf2 ah = (hf2){af, af};
            const int pix = hr * HC + (wc + kx);
            const int u0 = (pix * 4 + half * 2)     ^ (pix & 7);
            const int u1 = (pix * 4 + half * 2 + 1) ^ (pix & 7);
            union { uint4 u; hf2 h[4]; } xv, yv;
            xv.u = Vs[u0]; yv.u = Vs[u1];
            acch[0] += ah * xv.h[0];
            acch[1] += ah * xv.h[1];
            acch[2] += ah * xv.h[2];
            acch[3] += ah * xv.h[3];
            acch[4] += ah * yv.h[0];
            acch[5] += ah * yv.h[1];
            acch[6] += ah * yv.h[2];
            acch[7] += ah * yv.h[3];
        }
    }

    float* Ob = out + ((size_t)(n * 8 + head) * 32 + half * 16) * HW + p;
    #pragma unroll
    for (int i = 0; i < 8; ++i) {
        Ob[(size_t)(2*i)   * HW] = (float)acch[i][0] * inv;
        Ob[(size_t)(2*i+1) * HW] = (float)acch[i][1] * inv;
    }
}

// ---------------------------------------------------------------------------
extern "C" void kernel_launch(void* const* d_in, const int* in_sizes, int n_in,
                              void* d_out, int out_size, void* d_ws, size_t ws_size,
                              hipStream_t stream) {
    const float* x  = (const float*)d_in[0];   // (4, 256, 64, 64)
    const float* wq = (const float*)d_in[1];   // (768, 256)
    const float* bq = (const float*)d_in[2];   // (768,)
    float* out = (float*)d_out;                // (4, 256, 64, 64) fp32
    ushort16* qkv = (ushort16*)d_ws;           // fp16 [4][24][4096][32] = 25 MB

    dim3 g1(HW / 128, COUT / 128, 4);          // (32, 6, 4) = 768 blocks
    qkv_gemm_kernel<<<g1, 256, 0, stream>>>(x, wq, bq, qkv);

    dim3 g2(32, 8, 4);
    attn_kernel<<<g2, 256, 0, stream>>>(qkv, out);
}